// Round 2
// baseline (457.891 us; speedup 1.0000x reference)
//
#include <hip/hip_runtime.h>

// ShiftedWindowMSA — split-kernel version for MI355X (gfx950).
// prep_w:    w1 fp32 [256][768] -> wT bf16 [np(768)][k(256)] (transposed + column-permuted), bias perm.
// gemm_qkv:  per window (64-row M-tile incl 15 pad rows), 16 waves x 3 n-tiles; writes qkv bf16 to ws
//            in MFMA-fragment-friendly layout: Q,K = [w][h][q(64)][e(32)], V = [w][h][e(32)][k(64)].
// attn:      4 waves/block, wave = head; Q/K/V frags loaded directly from global (coalesced), P via
//            per-wave LDS; softmax in registers. Chunked over windows if ws_size is small.

typedef short bf16x8 __attribute__((ext_vector_type(8)));
typedef float f32x4 __attribute__((ext_vector_type(4)));
typedef unsigned short u16;
typedef u16 u16x8 __attribute__((ext_vector_type(8)));
typedef u16 u16x4 __attribute__((ext_vector_type(4)));

#define MFMA16 __builtin_amdgcn_mfma_f32_16x16x32_bf16

__device__ __forceinline__ u16 f2bf(float f) {
  union { float f; unsigned int u; } c; c.f = f;
  unsigned int uu = c.u;
  return (u16)((uu + 0x7fffu + ((uu >> 16) & 1u)) >> 16);
}

// ---------------- prep: transpose+permute w1 -> bf16, permute bias ----------------
// grid 64 blocks x 256 thr; block bid handles k rows [bid*4, bid*4+4).
__global__ void prep_w(const float* __restrict__ w1, const float* __restrict__ b1,
                       u16* __restrict__ wT, float* __restrict__ bp) {
  __shared__ u16 sW[4 * 768];
  const int tid = threadIdx.x;
  const int k0  = blockIdx.x * 4;
#pragma unroll
  for (int i = 0; i < 12; ++i) {               // coalesced read of 4 full w1 rows
    int f  = i * 256 + tid;                    // [0,3072)
    int kl = f / 768, n = f - kl * 768;
    sW[kl * 768 + n] = f2bf(w1[(k0 + kl) * 768 + n]);
  }
  __syncthreads();
#pragma unroll
  for (int j = 0; j < 3; ++j) {
    int np = tid * 3 + j;                      // permuted col: t*256 + hh*32 + ei
    int t = np >> 8, cc = np & 255;
    int hh = cc >> 5, ei = cc & 31;
    int n = (ei * 8 + hh) * 3 + t;             // original w1 column
    u16x4 o;
    o.x = sW[0 * 768 + n]; o.y = sW[1 * 768 + n];
    o.z = sW[2 * 768 + n]; o.w = sW[3 * 768 + n];
    *(u16x4*)(wT + np * 256 + k0) = o;
    if (blockIdx.x == 0) bp[np] = b1[n];
  }
}

// ---------------- kernel A: QKV GEMM ----------------
// qkv per-window block (u16 units): Q @ w'*49152 + hh*2048 + q*32 + ei
//                                   K @ +16384;  V @ +32768 + hh*2048 + ei*64 + q
__launch_bounds__(1024)
__global__ void gemm_qkv(const float* __restrict__ x, const u16* __restrict__ wT,
                         const float* __restrict__ bp, u16* __restrict__ qkv, int w0) {
  __shared__ __align__(16) char smem[32768];   // sA [64 rows][256 ch] bf16, chunk ^= row&7
  const int tid  = threadIdx.x;
  const int wave = tid >> 6;
  const int lane = tid & 63;
  const int quad = lane >> 4;
  const int l16  = lane & 15;
  const int wl   = blockIdx.x;                 // chunk-local window
  const int w    = w0 + wl;
  const int b = w >> 6, u = (w >> 3) & 7, v = w & 7;

  // stage x window (roll -4) -> sA bf16
  {
    const int xbase = b * (56 * 56 * 256);
#pragma unroll
    for (int it = 0; it < 2; ++it) {
      int idx = tid + it * 1024;               // 64 rows * 32 chunks(8ch)
      int row = idx >> 5;
      int ck  = idx & 31;
      char* dst = smem + row * 512 + ((ck ^ (row & 7)) << 4);
      u16x8 val{};
      if (row < 49) {
        int i = row / 7, j = row % 7;
        int sh = u * 7 + i + 4; if (sh >= 56) sh -= 56;
        int sw = v * 7 + j + 4; if (sw >= 56) sw -= 56;
        const float4* src = (const float4*)(x + xbase + (sh * 56 + sw) * 256 + ck * 8);
        float4 f0 = src[0];
        float4 f1 = src[1];
        val.s0 = f2bf(f0.x); val.s1 = f2bf(f0.y); val.s2 = f2bf(f0.z); val.s3 = f2bf(f0.w);
        val.s4 = f2bf(f1.x); val.s5 = f2bf(f1.y); val.s6 = f2bf(f1.z); val.s7 = f2bf(f1.w);
      }
      *(u16x8*)dst = val;
    }
  }
  __syncthreads();

  // GEMM: [64x256] @ [256x768]; wave owns 3 n-tiles
  f32x4 acc[4][3];
#pragma unroll
  for (int m = 0; m < 4; ++m)
#pragma unroll
    for (int i = 0; i < 3; ++i) acc[m][i] = (f32x4){0.f, 0.f, 0.f, 0.f};

  const int nt0 = wave * 3;
  const u16* gB[3];
#pragma unroll
  for (int i = 0; i < 3; ++i)
    gB[i] = wT + ((nt0 + i) * 16 + l16) * 256 + quad * 8;
  const char* aRow[4];
  int aSw[4];
#pragma unroll
  for (int m = 0; m < 4; ++m) {
    int row = m * 16 + l16;
    aRow[m] = smem + row * 512;
    aSw[m]  = row & 7;
  }

  bf16x8 bcur[3], bnxt[3];
#pragma unroll
  for (int i = 0; i < 3; ++i) bcur[i] = *(const bf16x8*)(gB[i]);

#pragma unroll
  for (int ks = 0; ks < 8; ++ks) {
    if (ks < 7) {
      const int k1 = ks + 1;
#pragma unroll
      for (int i = 0; i < 3; ++i) bnxt[i] = *(const bf16x8*)(gB[i] + k1 * 32);
    }
    bf16x8 acur[4];
#pragma unroll
    for (int m = 0; m < 4; ++m)
      acur[m] = *(const bf16x8*)(aRow[m] + (((ks * 4 + quad) ^ aSw[m]) << 4));
#pragma unroll
    for (int m = 0; m < 4; ++m)
#pragma unroll
      for (int i = 0; i < 3; ++i)
        acc[m][i] = MFMA16(acur[m], bcur[i], acc[m][i], 0, 0, 0);
    if (ks < 7) {
#pragma unroll
      for (int i = 0; i < 3; ++i) bcur[i] = bnxt[i];
    }
  }

  // epilogue: +bias, store bf16 to qkv (fragment-friendly layout)
  u16* qw = qkv + (size_t)wl * 49152;
#pragma unroll
  for (int i = 0; i < 3; ++i) {
    const int np = (nt0 + i) * 16 + l16;
    const float bi = bp[np];
    const int t  = np >> 8;
    const int hh = (np >> 5) & 7;
    const int ei = np & 31;
#pragma unroll
    for (int m = 0; m < 4; ++m)
#pragma unroll
      for (int r = 0; r < 4; ++r) {
        int q = m * 16 + quad * 4 + r;
        u16 val = f2bf(acc[m][i][r] + bi);
        if (t < 2)
          qw[t * 16384 + hh * 2048 + q * 32 + ei] = val;
        else
          qw[32768 + hh * 2048 + ei * 64 + q] = val;
      }
  }
}

// ---------------- kernel B: attention ----------------
// block = 256 thr = 4 waves; wave = head (hh = wave + 4*(bid&1)); window = bid>>1.
#define ATT_SMEM (4 * 4096 + 704)
__launch_bounds__(256, 3)
__global__ void attn(const u16* __restrict__ qkv, const float* __restrict__ pos,
                     float* __restrict__ out, int w0) {
  __shared__ __align__(16) char smem[ATT_SMEM];
  const int tid  = threadIdx.x;
  const int wave = tid >> 6;
  const int lane = tid & 63;
  const int quad = lane >> 4;
  const int l16  = lane & 15;
  const int wl   = blockIdx.x >> 1;
  const int hh   = wave + 4 * (blockIdx.x & 1);
  const int w    = w0 + wl;
  const int b = w >> 6, u = (w >> 3) & 7, v = w & 7;

  float* sPos = (float*)(smem + 4 * 4096);
  if (tid < 169) sPos[tid] = pos[tid];
  __syncthreads();

  const u16* qbase = qkv + (size_t)wl * 49152 + hh * 2048;

  // S = Q K^T  (frags straight from global, coalesced)
  bf16x8 qf[4], kf[4];
#pragma unroll
  for (int m = 0; m < 4; ++m) {
    qf[m] = *(const bf16x8*)(qbase + (m * 16 + l16) * 32 + quad * 8);
    kf[m] = *(const bf16x8*)(qbase + 16384 + (m * 16 + l16) * 32 + quad * 8);
  }
  f32x4 s[4][4];
#pragma unroll
  for (int m = 0; m < 4; ++m)
#pragma unroll
    for (int n = 0; n < 4; ++n) s[m][n] = (f32x4){0.f, 0.f, 0.f, 0.f};
#pragma unroll
  for (int m = 0; m < 4; ++m)
#pragma unroll
    for (int n = 0; n < 4; ++n)
      s[m][n] = MFMA16(qf[m], kf[n], s[m][n], 0, 0, 0);

  // scale + rel-pos bias + shift masks + softmax (C-layout registers)
  const bool rowm = (u == 7), colm = (v == 7);
  int ki[4], kj[4]; bool kok[4], kro[4], kco[4];
#pragma unroll
  for (int n = 0; n < 4; ++n) {
    int k = n * 16 + l16;
    ki[n] = k / 7; kj[n] = k % 7;
    kok[n] = (k < 49);
    kro[n] = (ki[n] >= 4);
    kco[n] = (kj[n] >= 4);
  }
  const float scale = 0.17677669529663687f;    // 1/sqrt(32)
  float rsum[4][4];
#pragma unroll
  for (int m = 0; m < 4; ++m) {
#pragma unroll
    for (int r = 0; r < 4; ++r) {
      int q = m * 16 + quad * 4 + r;
      int qi = q / 7, qj = q % 7;
      bool qro = (qi >= 4), qco = (qj >= 4);
      float vmax = -3e30f;
#pragma unroll
      for (int n = 0; n < 4; ++n) {
        bool bad = (!kok[n]) || (rowm && (qro != kro[n])) || (colm && (qco != kco[n]));
        float sv = bad ? -1e30f
                       : s[m][n][r] * scale + sPos[(ki[n] - qi + 6) * 13 + (kj[n] - qj + 6)];
        s[m][n][r] = sv;
        vmax = fmaxf(vmax, sv);
      }
      vmax = fmaxf(vmax, __shfl_xor(vmax, 1));
      vmax = fmaxf(vmax, __shfl_xor(vmax, 2));
      vmax = fmaxf(vmax, __shfl_xor(vmax, 4));
      vmax = fmaxf(vmax, __shfl_xor(vmax, 8));
      float sum = 0.f;
#pragma unroll
      for (int n = 0; n < 4; ++n) {
        float p = __expf(s[m][n][r] - vmax);
        s[m][n][r] = p;
        sum += p;
      }
      sum += __shfl_xor(sum, 1);
      sum += __shfl_xor(sum, 2);
      sum += __shfl_xor(sum, 4);
      sum += __shfl_xor(sum, 8);
      rsum[m][r] = sum;
    }
  }

  // PV via per-wave LDS P buffer, V frags straight from global
  char* sP = smem + wave * 4096;               // [64 q][32 k] bf16, chunk ^= row&3
  f32x4 o[4][2];
#pragma unroll
  for (int m = 0; m < 4; ++m) { o[m][0] = (f32x4){0.f,0.f,0.f,0.f}; o[m][1] = (f32x4){0.f,0.f,0.f,0.f}; }

#pragma unroll
  for (int ph = 0; ph < 2; ++ph) {
    if (ph == 1) asm volatile("s_waitcnt lgkmcnt(0)" ::: "memory");  // WAR on sP
#pragma unroll
    for (int n2 = 0; n2 < 2; ++n2) {
      int n  = ph * 2 + n2;
      int kh = n2 * 16 + l16;
      int kb = (kh & 7) << 1;
#pragma unroll
      for (int m = 0; m < 4; ++m)
#pragma unroll
        for (int r = 0; r < 4; ++r) {
          int row = m * 16 + quad * 4 + r;
          *(u16*)(sP + row * 64 + ((((kh >> 3) ^ (row & 3)) << 4) | kb)) = f2bf(s[m][n][r]);
        }
    }
    asm volatile("s_waitcnt lgkmcnt(0)" ::: "memory");               // RAW on sP
    bf16x8 vf[2], pa[4];
#pragma unroll
    for (int eh = 0; eh < 2; ++eh)
      vf[eh] = *(const bf16x8*)(qbase + 32768 + (eh * 16 + l16) * 64 + ph * 32 + quad * 8);
#pragma unroll
    for (int m = 0; m < 4; ++m) {
      int row = m * 16 + l16;
      pa[m] = *(const bf16x8*)(sP + row * 64 + ((quad ^ (row & 3)) << 4));
    }
#pragma unroll
    for (int m = 0; m < 4; ++m)
#pragma unroll
      for (int eh = 0; eh < 2; ++eh)
        o[m][eh] = MFMA16(pa[m], vf[eh], o[m][eh], 0, 0, 0);
  }

  // output: roll-back +3; channel c = ei*8 + head
#pragma unroll
  for (int m = 0; m < 4; ++m)
#pragma unroll
    for (int r = 0; r < 4; ++r) {
      int row = m * 16 + quad * 4 + r;
      if (row < 49) {
        int i = row / 7, j = row % 7;
        int dh = u * 7 + i + 3; if (dh >= 56) dh -= 56;
        int dw = v * 7 + j + 3; if (dw >= 56) dw -= 56;
        float inv = 1.f / rsum[m][r];
        float* op = out + ((b * 56 + dh) * 56 + dw) * 256 + hh;
        op[l16 * 8]        = o[m][0][r] * inv;
        op[(16 + l16) * 8] = o[m][1][r] * inv;
      }
    }
}

extern "C" void kernel_launch(void* const* d_in, const int* in_sizes, int n_in,
                              void* d_out, int out_size, void* d_ws, size_t ws_size,
                              hipStream_t stream) {
  const float* x   = (const float*)d_in[0];
  const float* w1  = (const float*)d_in[1];
  const float* b1  = (const float*)d_in[2];
  const float* pos = (const float*)d_in[3];

  u16*   wT = (u16*)d_ws;
  float* bp = (float*)((char*)d_ws + 768 * 256 * 2);
  u16*   qkv = (u16*)((char*)d_ws + 768 * 256 * 2 + 3072);  // chunk ring
  const size_t fixed = 768 * 256 * 2 + 3072;

  int wpc = 2048;                              // windows per chunk (qkv: wpc*98304 B)
  while (wpc > 64 && fixed + (size_t)wpc * 98304 > ws_size) wpc >>= 1;
  if (fixed + (size_t)wpc * 98304 > ws_size) return;  // visible failure

  prep_w<<<64, 256, 0, stream>>>(w1, b1, wT, bp);
  for (int w0 = 0; w0 < 2048; w0 += wpc) {
    gemm_qkv<<<wpc, 1024, 0, stream>>>(x, wT, bp, qkv, w0);
    attn<<<2 * wpc, 256, 0, stream>>>(qkv, pos, (float*)d_out, w0);
  }
}

// Round 3
// 427.265 us; speedup vs baseline: 1.0717x; 1.0717x over previous
//
#include <hip/hip_runtime.h>

// ShiftedWindowMSA fused v2 — MI355X (gfx950).
// 2048 blocks = windows; 512 thr = 8 waves; wave h owns head h end-to-end (GEMM + attention).
// w1 pre-permuted head-major: np = hh*96 + tile*16 + ci, tile = {Q0,Q1,K0,K1,V0,V1}.
// LDS: sA 32KB (x stage, shared) + 4KB/wave scratch + pos = 66KB -> 2 blocks/CU.
// One __syncthreads total; waves fully independent afterwards.

typedef short bf16x8 __attribute__((ext_vector_type(8)));
typedef float f32x4 __attribute__((ext_vector_type(4)));
typedef unsigned short u16;
typedef u16 u16x8 __attribute__((ext_vector_type(8)));
typedef u16 u16x4 __attribute__((ext_vector_type(4)));

#define MFMA16 __builtin_amdgcn_mfma_f32_16x16x32_bf16

__device__ __forceinline__ u16 f2bf(float f) {
  union { float f; unsigned int u; } c; c.f = f;
  unsigned int uu = c.u;
  return (u16)((uu + 0x7fffu + ((uu >> 16) & 1u)) >> 16);
}

#define OFF_A   0
#define OFF_SC  32768
#define OFF_POS 65536
#define SMEM_BYTES (65536 + 704)

// ---------------- prep: transpose+permute w1 -> bf16 (head-major), permute bias ----------------
__global__ void prep_w(const float* __restrict__ w1, const float* __restrict__ b1,
                       u16* __restrict__ wT, float* __restrict__ bp) {
  __shared__ u16 sW[4 * 768];
  const int tid = threadIdx.x;
  const int k0  = blockIdx.x * 4;
#pragma unroll
  for (int i = 0; i < 12; ++i) {               // coalesced: 4 full w1 rows
    int f  = i * 256 + tid;
    int kl = f / 768, n = f - kl * 768;
    sW[kl * 768 + n] = f2bf(w1[(k0 + kl) * 768 + n]);
  }
  __syncthreads();
#pragma unroll
  for (int j = 0; j < 3; ++j) {
    int np = tid * 3 + j;                      // np = hh*96 + tile*16 + ci
    int hh = np / 96, jj = np - hh * 96;
    int tile = jj >> 4, ci = jj & 15;
    int t  = tile >> 1;                        // 0=Q 1=K 2=V
    int ei = ((tile & 1) << 4) + ci;
    int n  = (ei * 8 + hh) * 3 + t;            // original w1 column
    u16x4 o;
    o.x = sW[0 * 768 + n]; o.y = sW[1 * 768 + n];
    o.z = sW[2 * 768 + n]; o.w = sW[3 * 768 + n];
    *(u16x4*)(wT + np * 256 + k0) = o;
    if (blockIdx.x == 0) bp[np] = b1[n];
  }
}

// 3-tile GEMM pass: acc[m][i] += A(64x256, LDS) * B(tiles tile0..tile0+2, global)
__device__ __forceinline__ void gemm3(const char* sA, const u16* gB0, int l16, int quad,
                                      f32x4 acc[4][3]) {
  bf16x8 bcur[3], bnxt[3];
#pragma unroll
  for (int i = 0; i < 3; ++i) bcur[i] = *(const bf16x8*)(gB0 + i * 4096);
#pragma unroll
  for (int ks = 0; ks < 8; ++ks) {
    if (ks < 7) {
#pragma unroll
      for (int i = 0; i < 3; ++i) bnxt[i] = *(const bf16x8*)(gB0 + i * 4096 + (ks + 1) * 32);
    }
    bf16x8 acur[4];
#pragma unroll
    for (int m = 0; m < 4; ++m) {
      int row = m * 16 + l16;
      acur[m] = *(const bf16x8*)(sA + row * 512 + (((ks * 4 + quad) ^ (row & 7)) << 4));
    }
#pragma unroll
    for (int m = 0; m < 4; ++m)
#pragma unroll
      for (int i = 0; i < 3; ++i)
        acc[m][i] = MFMA16(acur[m], bcur[i], acc[m][i], 0, 0, 0);
    if (ks < 7) {
#pragma unroll
      for (int i = 0; i < 3; ++i) bcur[i] = bnxt[i];
    }
  }
}

__launch_bounds__(512, 4)
__global__ void swin_fused(const float* __restrict__ x, const u16* __restrict__ wT,
                           const float* __restrict__ bp, const float* __restrict__ pos,
                           float* __restrict__ out) {
  __shared__ __align__(16) char smem[SMEM_BYTES];
  const int tid  = threadIdx.x;
  const int wave = tid >> 6;
  const int lane = tid & 63;
  const int quad = lane >> 4;
  const int l16  = lane & 15;
  const int blk  = blockIdx.x;
  const int b = blk >> 6, u = (blk >> 3) & 7, v = blk & 7;

  float* sPos = (float*)(smem + OFF_POS);
  if (tid < 169) sPos[tid] = pos[tid];

  // ---- stage x window (roll -4; -7//2 == -4 in Python) -> sA bf16, chunk ^= row&7 ----
  {
    const int xbase = b * (56 * 56 * 256);
#pragma unroll
    for (int it = 0; it < 4; ++it) {
      int idx = tid + it * 512;
      int row = idx >> 5;
      int ck  = idx & 31;
      char* dst = smem + OFF_A + row * 512 + ((ck ^ (row & 7)) << 4);
      u16x8 val{};
      if (row < 49) {
        int i = row / 7, j = row % 7;
        int sh = u * 7 + i + 4; if (sh >= 56) sh -= 56;
        int sw = v * 7 + j + 4; if (sw >= 56) sw -= 56;
        const float4* src = (const float4*)(x + xbase + (sh * 56 + sw) * 256 + ck * 8);
        float4 f0 = src[0];
        float4 f1 = src[1];
        val.s0 = f2bf(f0.x); val.s1 = f2bf(f0.y); val.s2 = f2bf(f0.z); val.s3 = f2bf(f0.w);
        val.s4 = f2bf(f1.x); val.s5 = f2bf(f1.y); val.s6 = f2bf(f1.z); val.s7 = f2bf(f1.w);
      }
      *(u16x8*)dst = val;
    }
  }
  __syncthreads();   // the ONLY block barrier

  const char* sA = smem + OFF_A;
  char* sc = smem + OFF_SC + wave * 4096;      // per-wave scratch
  const int hh = wave;
  bf16x8 qf[4], kf[4], vf[2][2];

  // ---- pass 0: tiles Q0,Q1,K0 ----
  {
    f32x4 acc[4][3];
#pragma unroll
    for (int m = 0; m < 4; ++m)
#pragma unroll
      for (int i = 0; i < 3; ++i) acc[m][i] = (f32x4){0.f, 0.f, 0.f, 0.f};
    const u16* gB0 = wT + ((hh * 6 + 0) * 16 + l16) * 256 + quad * 8;
    gemm3(sA, (const u16*)gB0, l16, quad, acc);

    // Q tiles -> scratch [q(64)][e(32)] bf16, chunk ^= q&3
#pragma unroll
    for (int i = 0; i < 2; ++i) {
      const float bi = bp[(hh * 6 + i) * 16 + l16];
      const int ch = i * 2 + (l16 >> 3), eb = (l16 & 7) << 1;
#pragma unroll
      for (int m = 0; m < 4; ++m)
#pragma unroll
        for (int r = 0; r < 4; ++r) {
          int q = m * 16 + quad * 4 + r;
          *(u16*)(sc + q * 64 + (((ch ^ (q & 3)) << 4) | eb)) = f2bf(acc[m][i][r] + bi);
        }
    }
    asm volatile("s_waitcnt lgkmcnt(0)" ::: "memory");
#pragma unroll
    for (int m = 0; m < 4; ++m) {
      int q = m * 16 + l16;
      qf[m] = *(const bf16x8*)(sc + q * 64 + ((quad ^ (q & 3)) << 4));
    }
    asm volatile("s_waitcnt lgkmcnt(0)" ::: "memory");   // qf landed before overwrite
    // K0 (e 0..15) -> scratch
    {
      const float bi = bp[(hh * 6 + 2) * 16 + l16];
      const int ch = (l16 >> 3), eb = (l16 & 7) << 1;
#pragma unroll
      for (int m = 0; m < 4; ++m)
#pragma unroll
        for (int r = 0; r < 4; ++r) {
          int q = m * 16 + quad * 4 + r;
          *(u16*)(sc + q * 64 + (((ch ^ (q & 3)) << 4) | eb)) = f2bf(acc[m][2][r] + bi);
        }
    }
  }

  // ---- pass 1: tiles K1,V0,V1 ----
  {
    f32x4 acc[4][3];
#pragma unroll
    for (int m = 0; m < 4; ++m)
#pragma unroll
      for (int i = 0; i < 3; ++i) acc[m][i] = (f32x4){0.f, 0.f, 0.f, 0.f};
    const u16* gB0 = wT + ((hh * 6 + 3) * 16 + l16) * 256 + quad * 8;
    gemm3(sA, (const u16*)gB0, l16, quad, acc);

    // K1 (e 16..31) -> scratch
    {
      const float bi = bp[(hh * 6 + 3) * 16 + l16];
      const int ch = 2 + (l16 >> 3), eb = (l16 & 7) << 1;
#pragma unroll
      for (int m = 0; m < 4; ++m)
#pragma unroll
        for (int r = 0; r < 4; ++r) {
          int q = m * 16 + quad * 4 + r;
          *(u16*)(sc + q * 64 + (((ch ^ (q & 3)) << 4) | eb)) = f2bf(acc[m][0][r] + bi);
        }
    }
    asm volatile("s_waitcnt lgkmcnt(0)" ::: "memory");
#pragma unroll
    for (int m = 0; m < 4; ++m) {
      int q = m * 16 + l16;
      kf[m] = *(const bf16x8*)(sc + q * 64 + ((quad ^ (q & 3)) << 4));
    }
    asm volatile("s_waitcnt lgkmcnt(0)" ::: "memory");   // kf landed
    // V tiles -> scratch [e(32)][key(64)] bf16, chunk ^= e&7; pack 4 keys/store
#pragma unroll
    for (int i = 1; i < 3; ++i) {
      const float bi = bp[(hh * 6 + 3 + i) * 16 + l16];
      const int e = (i - 1) * 16 + l16;
      const int esw = e & 7;
#pragma unroll
      for (int m = 0; m < 4; ++m) {
        int ch = 2 * m + (quad >> 1);
        u16x4 pk;
        pk.x = f2bf(acc[m][i][0] + bi); pk.y = f2bf(acc[m][i][1] + bi);
        pk.z = f2bf(acc[m][i][2] + bi); pk.w = f2bf(acc[m][i][3] + bi);
        *(u16x4*)(sc + e * 128 + (((ch ^ esw) << 4) | ((quad & 1) << 3))) = pk;
      }
    }
    asm volatile("s_waitcnt lgkmcnt(0)" ::: "memory");
#pragma unroll
    for (int ph = 0; ph < 2; ++ph)
#pragma unroll
      for (int n = 0; n < 2; ++n) {
        int e = n * 16 + l16;
        vf[ph][n] = *(const bf16x8*)(sc + e * 128 + (((ph * 4 + quad) ^ (e & 7)) << 4));
      }
    asm volatile("s_waitcnt lgkmcnt(0)" ::: "memory");   // vf landed; scratch free for P
  }

  // ---- S = Q K^T ----
  f32x4 s[4][4];
#pragma unroll
  for (int m = 0; m < 4; ++m)
#pragma unroll
    for (int n = 0; n < 4; ++n) s[m][n] = (f32x4){0.f, 0.f, 0.f, 0.f};
#pragma unroll
  for (int m = 0; m < 4; ++m)
#pragma unroll
    for (int n = 0; n < 4; ++n)
      s[m][n] = MFMA16(qf[m], kf[n], s[m][n], 0, 0, 0);

  // ---- scale + rel-pos bias + shift masks + softmax ----
  const bool rowm = (u == 7), colm = (v == 7);
  int ki[4], kj[4]; bool kok[4], kro[4], kco[4];
#pragma unroll
  for (int n = 0; n < 4; ++n) {
    int k = n * 16 + l16;
    ki[n] = k / 7; kj[n] = k % 7;
    kok[n] = (k < 49);
    kro[n] = (ki[n] >= 4);
    kco[n] = (kj[n] >= 4);
  }
  const float scale = 0.17677669529663687f;    // 1/sqrt(32)
  float rsum[4][4];
#pragma unroll
  for (int m = 0; m < 4; ++m) {
#pragma unroll
    for (int r = 0; r < 4; ++r) {
      int q = m * 16 + quad * 4 + r;
      int qi = q / 7, qj = q % 7;
      bool qro = (qi >= 4), qco = (qj >= 4);
      float vmax = -3e30f;
#pragma unroll
      for (int n = 0; n < 4; ++n) {
        bool bad = (!kok[n]) || (rowm && (qro != kro[n])) || (colm && (qco != kco[n]));
        float sv = bad ? -1e30f
                       : s[m][n][r] * scale + sPos[(ki[n] - qi + 6) * 13 + (kj[n] - qj + 6)];
        s[m][n][r] = sv;
        vmax = fmaxf(vmax, sv);
      }
      vmax = fmaxf(vmax, __shfl_xor(vmax, 1));
      vmax = fmaxf(vmax, __shfl_xor(vmax, 2));
      vmax = fmaxf(vmax, __shfl_xor(vmax, 4));
      vmax = fmaxf(vmax, __shfl_xor(vmax, 8));
      float sum = 0.f;
#pragma unroll
      for (int n = 0; n < 4; ++n) {
        float p = __expf(s[m][n][r] - vmax);
        s[m][n][r] = p;
        sum += p;
      }
      sum += __shfl_xor(sum, 1);
      sum += __shfl_xor(sum, 2);
      sum += __shfl_xor(sum, 4);
      sum += __shfl_xor(sum, 8);
      rsum[m][r] = sum;
    }
  }

  // ---- PV in two key-halves through scratch P [q(64)][key(32)], chunk ^= q&3 ----
  f32x4 o[4][2];
#pragma unroll
  for (int m = 0; m < 4; ++m) { o[m][0] = (f32x4){0.f,0.f,0.f,0.f}; o[m][1] = (f32x4){0.f,0.f,0.f,0.f}; }

#pragma unroll
  for (int ph = 0; ph < 2; ++ph) {
    if (ph == 1) asm volatile("s_waitcnt lgkmcnt(0)" ::: "memory");  // WAR on scratch
#pragma unroll
    for (int n2 = 0; n2 < 2; ++n2) {
      int n  = ph * 2 + n2;
      int kh = n2 * 16 + l16;
      int kb = (kh & 7) << 1;
#pragma unroll
      for (int m = 0; m < 4; ++m)
#pragma unroll
        for (int r = 0; r < 4; ++r) {
          int q = m * 16 + quad * 4 + r;
          *(u16*)(sc + q * 64 + ((((kh >> 3) ^ (q & 3)) << 4) | kb)) = f2bf(s[m][n][r]);
        }
    }
    asm volatile("s_waitcnt lgkmcnt(0)" ::: "memory");               // RAW on scratch
    bf16x8 pa[4];
#pragma unroll
    for (int m = 0; m < 4; ++m) {
      int q = m * 16 + l16;
      pa[m] = *(const bf16x8*)(sc + q * 64 + ((quad ^ (q & 3)) << 4));
    }
#pragma unroll
    for (int m = 0; m < 4; ++m)
#pragma unroll
      for (int n = 0; n < 2; ++n)
        o[m][n] = MFMA16(pa[m], vf[ph][n], o[m][n], 0, 0, 0);
  }

  // ---- output: roll-back +3; channel c = ei*8 + head ----
#pragma unroll
  for (int m = 0; m < 4; ++m)
#pragma unroll
    for (int r = 0; r < 4; ++r) {
      int row = m * 16 + quad * 4 + r;
      if (row < 49) {
        int i = row / 7, j = row % 7;
        int dh = u * 7 + i + 3; if (dh >= 56) dh -= 56;
        int dw = v * 7 + j + 3; if (dw >= 56) dw -= 56;
        float inv = 1.f / rsum[m][r];
        float* op = out + ((b * 56 + dh) * 56 + dw) * 256 + hh;
        op[l16 * 8]        = o[m][0][r] * inv;
        op[(16 + l16) * 8] = o[m][1][r] * inv;
      }
    }
}

extern "C" void kernel_launch(void* const* d_in, const int* in_sizes, int n_in,
                              void* d_out, int out_size, void* d_ws, size_t ws_size,
                              hipStream_t stream) {
  const float* x   = (const float*)d_in[0];
  const float* w1  = (const float*)d_in[1];
  const float* b1  = (const float*)d_in[2];
  const float* pos = (const float*)d_in[3];
  const size_t need = (size_t)768 * 256 * 2 + 768 * 4;
  if (ws_size < need) return;
  u16*   wT = (u16*)d_ws;
  float* bp = (float*)((char*)d_ws + 768 * 256 * 2);
  prep_w<<<64, 256, 0, stream>>>(w1, b1, wT, bp);
  swin_fused<<<2048, 512, 0, stream>>>(x, wT, bp, pos, (float*)d_out);
}